// Round 1
// baseline (606.924 us; speedup 1.0000x reference)
//
#include <hip/hip_runtime.h>
#include <hip/hip_bf16.h>

#define N_AGENTS 50000
#define N_NEI    1600000
#define ROWS     128
#define PHI_BLOCKS (N_NEI / ROWS)   // 12500, exact

typedef __bf16 bf16_t;
typedef __attribute__((ext_vector_type(8))) __bf16 bf16x8;
typedef __attribute__((ext_vector_type(4))) __bf16 bf16x4;
typedef __attribute__((ext_vector_type(4))) float  f32x4;

#define SA 72   // bf16 tile leading dim (64+8): breaks 128B-stride bank aliasing, keeps 16B align
#define SO 66   // fp32 out tile leading dim

// ---------------------------------------------------------------------------
// phi kernel: per block of 128 sorted neighbor rows:
//   X(128x64) -> H1 = relu(X@W1+b1) -> H2 = H1@W2+b2  (bf16 MFMA, fp32 accum)
//   then per-wave segmented sum over its own 32 rows -> atomicAdd into summ.
// ---------------------------------------------------------------------------
__global__ __launch_bounds__(256) void phi_kernel(
    const float* __restrict__ nb,
    const float* __restrict__ w1g, const float* __restrict__ b1g,
    const float* __restrict__ w2g, const float* __restrict__ b2g,
    const int* __restrict__ seg, float* __restrict__ summ)
{
  __shared__ __align__(16) union {
    struct {
      bf16_t A[ROWS * SA];      // 18432 B : X tile, then H1 tile (bf16)
      bf16_t Wt[2][64 * SA];    // 18432 B : W1^T, W2^T (bf16, [n][k])
    } s;
    float outb[ROWS * SO];      // 33792 B : H2 fp32 (aliases A + part of Wt)
  } u;
  __shared__ float biasf[2][64];
  __shared__ int sid[ROWS + 4];

  const int tid  = threadIdx.x;
  const int w    = tid >> 6;      // wave 0..3
  const int lane = tid & 63;
  const int m16  = lane & 15;     // A row / B col / D col within 16-tile
  const int q    = lane >> 4;     // quad 0..3
  const int base_row = blockIdx.x * ROWS;

  // ---- stage segment ids + biases
  if (tid < ROWS) sid[tid] = seg[base_row + tid];
  if (tid < 64) biasf[0][tid] = b1g[tid];
  else if (tid < 128) biasf[1][tid - 64] = b2g[tid - 64];

  // ---- stage weights transposed to [n][k], bf16 (tiny; L2-resident globally)
  for (int i = tid; i < 4096; i += 256) {
    int k = i >> 6, n = i & 63;
    u.s.Wt[0][n * SA + k] = (bf16_t)w1g[i];
    u.s.Wt[1][n * SA + k] = (bf16_t)w2g[i];
  }

  // ---- stage X tile (coalesced float4), convert to bf16
  {
    const float4* np4 = (const float4*)(nb + (size_t)base_row * 64);
    #pragma unroll
    for (int it = 0; it < 8; ++it) {
      int j = tid + it * 256;            // float4 index within tile [0,2048)
      float4 v = np4[j];
      int row = j >> 4, col = (j & 15) * 4;
      bf16x4 p = { (bf16_t)v.x, (bf16_t)v.y, (bf16_t)v.z, (bf16_t)v.w };
      *(bf16x4*)&u.s.A[row * SA + col] = p;
    }
  }
  __syncthreads();

  const int rb = w * 32;                 // this wave's 32-row stripe
  bf16x8 bfr[4][2], afr[2][2];
  f32x4  acc[2][4];

  // ================= GEMM1: H1 = relu(X @ W1 + b1) =================
  #pragma unroll
  for (int tn = 0; tn < 4; ++tn)
    #pragma unroll
    for (int kb = 0; kb < 2; ++kb)
      bfr[tn][kb] = *(const bf16x8*)&u.s.Wt[0][(tn * 16 + m16) * SA + kb * 32 + q * 8];
  #pragma unroll
  for (int tm = 0; tm < 2; ++tm)
    #pragma unroll
    for (int kb = 0; kb < 2; ++kb)
      afr[tm][kb] = *(const bf16x8*)&u.s.A[(rb + tm * 16 + m16) * SA + kb * 32 + q * 8];
  #pragma unroll
  for (int tm = 0; tm < 2; ++tm)
    #pragma unroll
    for (int tn = 0; tn < 4; ++tn) {
      f32x4 a = {0.f, 0.f, 0.f, 0.f};
      a = __builtin_amdgcn_mfma_f32_16x16x32_bf16(afr[tm][0], bfr[tn][0], a, 0, 0, 0);
      a = __builtin_amdgcn_mfma_f32_16x16x32_bf16(afr[tm][1], bfr[tn][1], a, 0, 0, 0);
      acc[tm][tn] = a;
    }
  // write H1 back over X (bf16). Wave touches only its own rows -> no barrier.
  // All A-fragment reads above precede these writes in program order; LDS ops
  // within a wave execute in order.
  #pragma unroll
  for (int tm = 0; tm < 2; ++tm)
    #pragma unroll
    for (int tn = 0; tn < 4; ++tn) {
      float bv = biasf[0][tn * 16 + m16];
      #pragma unroll
      for (int i = 0; i < 4; ++i) {
        float hv = fmaxf(acc[tm][tn][i] + bv, 0.f);
        u.s.A[(rb + tm * 16 + q * 4 + i) * SA + tn * 16 + m16] = (bf16_t)hv;
      }
    }

  // ================= GEMM2: H2 = H1 @ W2 + b2 =================
  // Preload ALL fragments before the barrier: outb aliases A + Wt.
  #pragma unroll
  for (int tn = 0; tn < 4; ++tn)
    #pragma unroll
    for (int kb = 0; kb < 2; ++kb)
      bfr[tn][kb] = *(const bf16x8*)&u.s.Wt[1][(tn * 16 + m16) * SA + kb * 32 + q * 8];
  #pragma unroll
  for (int tm = 0; tm < 2; ++tm)
    #pragma unroll
    for (int kb = 0; kb < 2; ++kb)
      afr[tm][kb] = *(const bf16x8*)&u.s.A[(rb + tm * 16 + m16) * SA + kb * 32 + q * 8];
  __syncthreads();   // everyone done reading A/Wt; outb may now overwrite them

  #pragma unroll
  for (int tm = 0; tm < 2; ++tm)
    #pragma unroll
    for (int tn = 0; tn < 4; ++tn) {
      f32x4 a = {0.f, 0.f, 0.f, 0.f};
      a = __builtin_amdgcn_mfma_f32_16x16x32_bf16(afr[tm][0], bfr[tn][0], a, 0, 0, 0);
      a = __builtin_amdgcn_mfma_f32_16x16x32_bf16(afr[tm][1], bfr[tn][1], a, 0, 0, 0);
      acc[tm][tn] = a;
    }
  #pragma unroll
  for (int tm = 0; tm < 2; ++tm)
    #pragma unroll
    for (int tn = 0; tn < 4; ++tn) {
      float bv = biasf[1][tn * 16 + m16];
      #pragma unroll
      for (int i = 0; i < 4; ++i)
        u.outb[(rb + tm * 16 + q * 4 + i) * SO + tn * 16 + m16] = acc[tm][tn][i] + bv;
    }

  // ---- segmented reduction: wave w owns rows [rb, rb+32), lane owns col=lane.
  // segment_ids are sorted -> detect run boundaries; one atomic per run.
  float racc = 0.f;
  for (int r = rb; r < rb + 32; ++r) {
    racc += u.outb[r * SO + lane];
    int sr = sid[r];
    if (r == rb + 31 || sid[r + 1] != sr) {   // short-circuit: no sid[128] read
      atomicAdd(summ + (size_t)sr * 64 + lane, racc);
      racc = 0.f;
    }
  }
}

// ---------------------------------------------------------------------------
// rho kernel: fp32 throughout (accuracy on pooled values). One thread/agent.
// Weights broadcast from LDS (uniform address -> conflict-free).
// ---------------------------------------------------------------------------
__global__ __launch_bounds__(256) void rho_kernel(
    const float* __restrict__ summ,
    const float* __restrict__ w1g, const float* __restrict__ b1g,
    const float* __restrict__ w2g, const float* __restrict__ b2g,
    float* __restrict__ out)
{
  __shared__ float sw1[64 * 64];
  __shared__ float sw2[128];
  __shared__ float sb1[64];
  __shared__ float sb2[2];
  const int tid = threadIdx.x;
  for (int i = tid; i < 4096; i += 256) sw1[i] = w1g[i];
  if (tid < 128) sw2[tid] = w2g[tid];
  if (tid < 64)  sb1[tid] = b1g[tid];
  if (tid < 2)   sb2[tid] = b2g[tid];
  __syncthreads();

  int a = blockIdx.x * 256 + tid;
  if (a >= N_AGENTS) return;

  float x[64];
  const float4* xr = (const float4*)(summ + (size_t)a * 64);
  #pragma unroll
  for (int i = 0; i < 16; ++i) {
    float4 v = xr[i];
    x[4*i] = v.x; x[4*i+1] = v.y; x[4*i+2] = v.z; x[4*i+3] = v.w;
  }

  float o0 = sb2[0], o1 = sb2[1];
  for (int n = 0; n < 64; ++n) {
    float a0 = sb1[n], a1 = 0.f, a2 = 0.f, a3 = 0.f;
    #pragma unroll
    for (int k = 0; k < 64; k += 4) {
      a0 = fmaf(x[k],     sw1[(k)     * 64 + n], a0);
      a1 = fmaf(x[k + 1], sw1[(k + 1) * 64 + n], a1);
      a2 = fmaf(x[k + 2], sw1[(k + 2) * 64 + n], a2);
      a3 = fmaf(x[k + 3], sw1[(k + 3) * 64 + n], a3);
    }
    float h = fmaxf((a0 + a1) + (a2 + a3), 0.f);
    o0 = fmaf(h, sw2[2 * n],     o0);
    o1 = fmaf(h, sw2[2 * n + 1], o1);
  }
  *(float2*)(out + (size_t)a * 2) = make_float2(o0, o1);
}

// ---------------------------------------------------------------------------
extern "C" void kernel_launch(void* const* d_in, const int* in_sizes, int n_in,
                              void* d_out, int out_size, void* d_ws, size_t ws_size,
                              hipStream_t stream) {
  const float* neighbors = (const float*)d_in[0];
  const float* phi_w1    = (const float*)d_in[1];
  const float* phi_b1    = (const float*)d_in[2];
  const float* phi_w2    = (const float*)d_in[3];
  const float* phi_b2    = (const float*)d_in[4];
  const float* rho_w1    = (const float*)d_in[5];
  const float* rho_b1    = (const float*)d_in[6];
  const float* rho_w2    = (const float*)d_in[7];
  const float* rho_b2    = (const float*)d_in[8];
  const int*   seg       = (const int*)d_in[9];
  float* out  = (float*)d_out;
  float* summ = (float*)d_ws;   // 50000 x 64 fp32 = 12.8 MB scratch

  hipMemsetAsync(summ, 0, (size_t)N_AGENTS * 64 * sizeof(float), stream);
  phi_kernel<<<PHI_BLOCKS, 256, 0, stream>>>(neighbors, phi_w1, phi_b1,
                                             phi_w2, phi_b2, seg, summ);
  rho_kernel<<<(N_AGENTS + 255) / 256, 256, 0, stream>>>(summ, rho_w1, rho_b1,
                                                         rho_w2, rho_b2, out);
}